// Round 7
// baseline (288.701 us; speedup 1.0000x reference)
//
#include <hip/hip_runtime.h>

#define NN 25000
#define EE 400000
#define FIN 128
#define FE 16
#define CH 32
#define SLOPE 0.01f
#define PROJ_BLOCKS 391   // ceil(25000/64)
#define AUX_BLOCKS 32
#define WROW 24                      // WtL row stride in shorts (48B); bias at k=16
#define WTP_SHORTS (1024 * WROW + 8) // +16B zero tail (quad-3 read past row 1023)

typedef __attribute__((ext_vector_type(8))) short bf16x8;
typedef __attribute__((ext_vector_type(4))) float f32x4;

__device__ __forceinline__ float lrelu(float v) { return fmaxf(v, SLOPE * v); }

__device__ __forceinline__ f32x4 lrelu4(f32x4 v) {
    f32x4 s = v * SLOPE;
#if __has_builtin(__builtin_elementwise_max)
    return __builtin_elementwise_max(v, s);   // v_pk_max_f32
#else
    f32x4 r;
    r[0] = fmaxf(v[0], s[0]); r[1] = fmaxf(v[1], s[1]);
    r[2] = fmaxf(v[2], s[2]); r[3] = fmaxf(v[3], s[3]);
    return r;
#endif
}

// float -> bf16 bits, round-to-nearest-even
__device__ __forceinline__ unsigned short f2bf(float f) {
    union { float f; unsigned u; } v; v.f = f;
    unsigned r = (v.u + 0x7fffu + ((v.u >> 16) & 1u)) >> 16;
    return (unsigned short)r;
}

// ---------------- Kernel 1: fused prep
// blocks [0, PROJ): h_bf = bf16(leaky(x @ W_in + b_in)) via MFMA (64 nodes/block)
// blocks [PROJ, +4): WtP rows (W_edge^T bf16 + bias@k16 + zero pad)
// blocks [PROJ+4, +32): zero aggr; ea_bf = bf16(ea)
__global__ void __launch_bounds__(256)
k_pre(const float* __restrict__ x, const float* __restrict__ W_in,
      const float* __restrict__ b_in, const float* __restrict__ W_edge,
      const float* __restrict__ b_edge, const float* __restrict__ ea,
      unsigned short* __restrict__ h_bf, float* __restrict__ aggr,
      short* __restrict__ WtP, short* __restrict__ ea_bf) {
    __shared__ short Wt1[CH * 136];
    int tid = threadIdx.x;

    if (blockIdx.x >= PROJ_BLOCKS) {
        int ab = blockIdx.x - PROJ_BLOCKS;
        if (ab < 4) {
            int co = ab * 256 + tid;                       // 0..1023
            short row[WROW] __attribute__((aligned(16)));
#pragma unroll
            for (int k = 0; k < 16; k++) row[k] = (short)f2bf(W_edge[k * 1024 + co]);
            row[16] = (short)f2bf(b_edge[co]);
#pragma unroll
            for (int k = 17; k < WROW; k++) row[k] = 0;
            uint4* dstp = (uint4*)(WtP + co * WROW);       // co*48B, 16B-aligned
            dstp[0] = ((uint4*)row)[0]; dstp[1] = ((uint4*)row)[1]; dstp[2] = ((uint4*)row)[2];
            if (ab == 0 && tid < 8) WtP[1024 * WROW + tid] = 0;   // tail pad
        } else {
            int t = (ab - 4) * 256 + tid;
            float4 z = make_float4(0.f, 0.f, 0.f, 0.f);
            for (int i = t; i < NN * CH / 4; i += (AUX_BLOCKS - 4) * 256)
                ((float4*)aggr)[i] = z;
            for (int e = t; e < EE; e += (AUX_BLOCKS - 4) * 256) {
                const float4* p = (const float4*)(ea + (size_t)e * FE);
                float4 a0 = p[0], a1 = p[1], a2 = p[2], a3 = p[3];
                short rr[16] __attribute__((aligned(16)));
                rr[0]=(short)f2bf(a0.x); rr[1]=(short)f2bf(a0.y); rr[2]=(short)f2bf(a0.z); rr[3]=(short)f2bf(a0.w);
                rr[4]=(short)f2bf(a1.x); rr[5]=(short)f2bf(a1.y); rr[6]=(short)f2bf(a1.z); rr[7]=(short)f2bf(a1.w);
                rr[8]=(short)f2bf(a2.x); rr[9]=(short)f2bf(a2.y); rr[10]=(short)f2bf(a2.z); rr[11]=(short)f2bf(a2.w);
                rr[12]=(short)f2bf(a3.x); rr[13]=(short)f2bf(a3.y); rr[14]=(short)f2bf(a3.z); rr[15]=(short)f2bf(a3.w);
                uint4* q = (uint4*)(ea_bf + (size_t)e * FE);
                q[0] = ((uint4*)rr)[0]; q[1] = ((uint4*)rr)[1];
            }
        }
        return;
    }

    // ---- input projection ----
#pragma unroll
    for (int i = 0; i < 16; i++) {
        int id = tid + 256 * i;           // id = k*32 + c
        int k = id >> 5, c = id & 31;
        Wt1[c * 136 + k] = (short)f2bf(W_in[id]);
    }
    __syncthreads();

    int wave = tid >> 6, lane = tid & 63;
    int n16 = lane & 15, quad = lane >> 4;
    int node0 = blockIdx.x * 64 + wave * 16;

    f32x4 D[2];
#pragma unroll
    for (int ch = 0; ch < 2; ch++) {
        float bb = b_in[ch * 16 + n16];
        D[ch] = (f32x4){bb, bb, bb, bb};
    }
    int arow = node0 + n16; if (arow >= NN) arow = NN - 1;
#pragma unroll
    for (int kb = 0; kb < 4; kb++) {
        const float4* xp = (const float4*)(x + (size_t)arow * FIN + kb * 32 + quad * 8);
        float4 xa = xp[0], xb = xp[1];
        bf16x8 A = (bf16x8){(short)f2bf(xa.x), (short)f2bf(xa.y), (short)f2bf(xa.z), (short)f2bf(xa.w),
                            (short)f2bf(xb.x), (short)f2bf(xb.y), (short)f2bf(xb.z), (short)f2bf(xb.w)};
#pragma unroll
        for (int ch = 0; ch < 2; ch++) {
            bf16x8 B = *(const bf16x8*)&Wt1[(ch * 16 + n16) * 136 + kb * 32 + quad * 8];
            D[ch] = __builtin_amdgcn_mfma_f32_16x16x32_bf16(A, B, D[ch], 0, 0, 0);
        }
    }
#pragma unroll
    for (int ch = 0; ch < 2; ch++)
#pragma unroll
        for (int r = 0; r < 4; r++) {
            int nn = node0 + quad * 4 + r;
            if (nn < NN) h_bf[(size_t)nn * CH + ch * 16 + n16] = f2bf(lrelu(D[ch][r]));
        }
}

// ---------------- Kernel 2: fused edge-NN + matvec + scatter
// Block = 256 thr = 4 waves; 256 edges/block; wave = 4 tiles x 16 edges.
// LDS: WtL 49.2KB + hsB(bf16) 16.9KB = 66.1KB -> 2 blocks/CU.
__global__ void __launch_bounds__(256, 2)
k_edge(const short* __restrict__ WtP,    // [1024][24] bf16 image (+pad)
       const short* __restrict__ ea_bf,  // [EE][16] bf16
       const int* __restrict__ src,
       const int* __restrict__ dst,
       const unsigned short* __restrict__ h_bf,  // [NN][32] bf16
       float* __restrict__ aggr) {
    __shared__ short WtL[WTP_SHORTS];          // 49168 B
    __shared__ unsigned short hsB[CH * 264];   // 16896 B, hsB[c][e], bf16

    int tid = threadIdx.x;
    int e0 = blockIdx.x * 256;

    // stage WtL: 3073 uint4 vector copies
#pragma unroll
    for (int j = 0; j < 13; j++) {
        int idx = tid + 256 * j;
        if (idx < WTP_SHORTS / 8) ((uint4*)WtL)[idx] = ((const uint4*)WtP)[idx];
    }
    // stage hsB (transposed, bf16): thread = block-edge
    {
        int e = e0 + tid; if (e >= EE) e = EE - 1;
        int s = src[e];
        const uint4* hp = (const uint4*)(h_bf + (size_t)s * CH);
        uint4 r0 = hp[0], r1 = hp[1], r2 = hp[2], r3 = hp[3];
        unsigned w[8] = {r0.x, r0.y, r0.z, r0.w, r1.x, r1.y, r1.z, r1.w};
        unsigned w2[8] = {r2.x, r2.y, r2.z, r2.w, r3.x, r3.y, r3.z, r3.w};
#pragma unroll
        for (int c2 = 0; c2 < 8; c2++) {
            hsB[(2 * c2) * 264 + tid]     = (unsigned short)(w[c2] & 0xffffu);
            hsB[(2 * c2 + 1) * 264 + tid] = (unsigned short)(w[c2] >> 16);
            hsB[(16 + 2 * c2) * 264 + tid]     = (unsigned short)(w2[c2] & 0xffffu);
            hsB[(16 + 2 * c2 + 1) * 264 + tid] = (unsigned short)(w2[c2] >> 16);
        }
    }
    __syncthreads();

    int wave = tid >> 6, lane = tid & 63;
    int n16 = lane & 15, quad = lane >> 4;
    int ebase = e0 + wave * 64;          // this wave's first edge
    int lbase = wave * 64;               // block-local

    // A fragments: quads 0,1 = ea_bf; quad 2 = {1.0,...} (bias row k=16); quad 3 = 0
    bf16x8 A[4];
#pragma unroll
    for (int t = 0; t < 4; t++) {
        bf16x8 a = (bf16x8){0,0,0,0,0,0,0,0};
        if (quad < 2) {
            int e = ebase + t * 16 + n16; if (e >= EE) e = EE - 1;
            a = *(const bf16x8*)(ea_bf + (size_t)e * FE + quad * 8);
        } else if (quad == 2) {
            a[0] = (short)0x3F80;        // bf16 1.0 -> multiplies bias at k=16
        }
        A[t] = a;
    }

    f32x4 m[4][2];
#pragma unroll
    for (int t = 0; t < 4; t++) { m[t][0] = (f32x4){0,0,0,0}; m[t][1] = m[t][0]; }
    const f32x4 Z = (f32x4){0,0,0,0};

    const short* Bb = WtL + n16 * WROW + quad * 8;           // + cb*(16*WROW) imm
    const unsigned short* hb = hsB + lbase + quad * 4;       // + c*264 + t*16 imm

#pragma unroll 4
    for (int c = 0; c < 32; c++) {
        f32x4 hf[4];
#pragma unroll
        for (int t = 0; t < 4; t++) {
            uint2 raw = *(const uint2*)(hb + c * 264 + t * 16);   // ds_read_b64
            hf[t][0] = __uint_as_float(raw.x << 16);
            hf[t][1] = __uint_as_float(raw.x & 0xffff0000u);
            hf[t][2] = __uint_as_float(raw.y << 16);
            hf[t][3] = __uint_as_float(raw.y & 0xffff0000u);
        }
#pragma unroll
        for (int oh = 0; oh < 2; oh++) {
            bf16x8 B = *(const bf16x8*)(Bb + (c * 2 + oh) * (16 * WROW));
#pragma unroll
            for (int t = 0; t < 4; t++) {
                f32x4 D = __builtin_amdgcn_mfma_f32_16x16x32_bf16(A[t], B, Z, 0, 0, 0);
                m[t][oh] += hf[t] * lrelu4(D);    // v_pk_fma_f32
            }
        }
    }

    // scatter: lane holds msg for edge (tile t, row quad*4+r), col o = oh*16 + n16
#pragma unroll
    for (int t = 0; t < 4; t++)
#pragma unroll
        for (int r = 0; r < 4; r++) {
            int e = ebase + t * 16 + quad * 4 + r;
            if (e < EE) {
                int d = dst[e];
                unsafeAtomicAdd(&aggr[(size_t)d * CH + n16],      m[t][0][r]);
                unsafeAtomicAdd(&aggr[(size_t)d * CH + 16 + n16], m[t][1][r]);
            }
        }
}

// ---------------- Kernel 3 (MFMA): out = leaky(aggr + h@W_root + b_conv) @ W_out + b_out
__global__ void __launch_bounds__(256)
k_node(const float* __restrict__ aggr,
       const unsigned short* __restrict__ h_bf,
       const float* __restrict__ W_root,
       const float* __restrict__ b_conv,
       const float* __restrict__ W_out,
       const float* __restrict__ b_out,
       float* __restrict__ out) {
    __shared__ short WrB[CH * 40];   // W_root^T bf16: [o][c], stride 40 shorts
    __shared__ float WoS[CH];
    int tid = threadIdx.x;
    if (tid < 128) {
        int o = tid >> 2, c0 = (tid & 3) * 8;
        short tmp[8] __attribute__((aligned(16)));
#pragma unroll
        for (int j = 0; j < 8; j++) tmp[j] = (short)f2bf(W_root[(c0 + j) * CH + o]);
        *(bf16x8*)&WrB[o * 40 + c0] = *(bf16x8*)tmp;
    } else if (tid < 160) {
        WoS[tid - 128] = W_out[tid - 128];
    }
    __syncthreads();

    int wave = tid >> 6, lane = tid & 63;
    int n16 = lane & 15, quad = lane >> 4;
    int node0 = blockIdx.x * 64 + wave * 16;

    int arow = node0 + n16; if (arow >= NN) arow = NN - 1;
    bf16x8 A = *(const bf16x8*)(h_bf + (size_t)arow * CH + quad * 8);
    float bc0 = b_conv[n16], bc1 = b_conv[16 + n16];
    f32x4 C0, C1;
#pragma unroll
    for (int r = 0; r < 4; r++) {
        int nr = node0 + quad * 4 + r; int cr = (nr < NN) ? nr : NN - 1;
        C0[r] = aggr[(size_t)cr * CH + n16] + bc0;
        C1[r] = aggr[(size_t)cr * CH + 16 + n16] + bc1;
    }
    bf16x8 B0 = *(const bf16x8*)&WrB[n16 * 40 + quad * 8];
    bf16x8 B1 = *(const bf16x8*)&WrB[(16 + n16) * 40 + quad * 8];
    f32x4 D0 = __builtin_amdgcn_mfma_f32_16x16x32_bf16(A, B0, C0, 0, 0, 0);
    f32x4 D1 = __builtin_amdgcn_mfma_f32_16x16x32_bf16(A, B1, C1, 0, 0, 0);

    float w0 = WoS[n16], w1 = WoS[16 + n16];
    f32x4 p;
#pragma unroll
    for (int r = 0; r < 4; r++)
        p[r] = lrelu(D0[r]) * w0 + lrelu(D1[r]) * w1;
#pragma unroll
    for (int mk = 1; mk < 16; mk <<= 1) {
#pragma unroll
        for (int r = 0; r < 4; r++) p[r] += __shfl_xor(p[r], mk, 64);
    }
    if (n16 == 0) {
        float bo = b_out[0];
#pragma unroll
        for (int r = 0; r < 4; r++) {
            int nr = node0 + quad * 4 + r;
            if (nr < NN) out[nr] = p[r] + bo;
        }
    }
}

extern "C" void kernel_launch(void* const* d_in, const int* in_sizes, int n_in,
                              void* d_out, int out_size, void* d_ws, size_t ws_size,
                              hipStream_t stream) {
    const float* x      = (const float*)d_in[0];
    const int*   ei     = (const int*)d_in[1];
    const float* ea     = (const float*)d_in[2];
    const float* W_in   = (const float*)d_in[3];
    const float* b_in   = (const float*)d_in[4];
    const float* W_edge = (const float*)d_in[5];
    const float* b_edge = (const float*)d_in[6];
    const float* W_root = (const float*)d_in[7];
    const float* b_conv = (const float*)d_in[8];
    const float* W_out  = (const float*)d_in[9];
    const float* b_out  = (const float*)d_in[10];
    float* out = (float*)d_out;
    float* aggr = (float*)d_ws;                                 // [NN*CH] f32
    unsigned short* h_bf = (unsigned short*)(aggr + (size_t)NN * CH); // [NN*CH] bf16
    short* WtP  = (short*)(h_bf + (size_t)NN * CH);             // [WTP_SHORTS]
    short* ea_bf = WtP + WTP_SHORTS;                            // [EE*16] bf16

    k_pre<<<PROJ_BLOCKS + AUX_BLOCKS, 256, 0, stream>>>(x, W_in, b_in, W_edge, b_edge,
                                                        ea, h_bf, aggr, WtP, ea_bf);
    k_edge<<<(EE + 255) / 256, 256, 0, stream>>>(WtP, ea_bf, ei, ei + EE, h_bf, aggr);
    k_node<<<PROJ_BLOCKS, 256, 0, stream>>>(aggr, h_bf, W_root, b_conv, W_out, b_out, out);
}

// Round 8
// 184.509 us; speedup vs baseline: 1.5647x; 1.5647x over previous
//
#include <hip/hip_runtime.h>

#define NN 25000
#define EE 400000
#define FIN 128
#define FE 16
#define CH 32
#define SLOPE 0.01f
#define PROJ_BLOCKS 391   // ceil(25000/64)
#define AUX_BLOCKS 64     // 4 WtP-build + 60 aggr-zero
#define WROW 24                      // WtL row stride in shorts (48B); bias at k=16
#define WTP_SHORTS (1024 * WROW + 8) // +16B zero tail (quad-3 read past row 1023)

typedef __attribute__((ext_vector_type(8))) short bf16x8;
typedef __attribute__((ext_vector_type(4))) float f32x4;

__device__ __forceinline__ float lrelu(float v) { return fmaxf(v, SLOPE * v); }

__device__ __forceinline__ f32x4 lrelu4(f32x4 v) {
    f32x4 s = v * SLOPE;
#if __has_builtin(__builtin_elementwise_max)
    return __builtin_elementwise_max(v, s);   // v_pk_max_f32
#else
    f32x4 r;
    r[0] = fmaxf(v[0], s[0]); r[1] = fmaxf(v[1], s[1]);
    r[2] = fmaxf(v[2], s[2]); r[3] = fmaxf(v[3], s[3]);
    return r;
#endif
}

// float -> bf16 bits, round-to-nearest-even
__device__ __forceinline__ unsigned short f2bf(float f) {
    union { float f; unsigned u; } v; v.f = f;
    unsigned r = (v.u + 0x7fffu + ((v.u >> 16) & 1u)) >> 16;
    return (unsigned short)r;
}

// ---------------- Kernel 1: fused prep
// blocks [0, PROJ): h_bf = bf16(leaky(x @ W_in + b_in)) via MFMA (64 nodes/block)
// blocks [PROJ, +4): WtP rows (W_edge^T bf16 + bias@k16 + zero pad)
// blocks [PROJ+4, +64): zero aggr
__global__ void __launch_bounds__(256)
k_pre(const float* __restrict__ x, const float* __restrict__ W_in,
      const float* __restrict__ b_in, const float* __restrict__ W_edge,
      const float* __restrict__ b_edge,
      unsigned short* __restrict__ h_bf, float* __restrict__ aggr,
      short* __restrict__ WtP) {
    __shared__ short Wt1[CH * 136];
    int tid = threadIdx.x;

    if (blockIdx.x >= PROJ_BLOCKS) {
        int ab = blockIdx.x - PROJ_BLOCKS;
        if (ab < 4) {
            int co = ab * 256 + tid;                       // 0..1023
            short row[WROW] __attribute__((aligned(16)));
#pragma unroll
            for (int k = 0; k < 16; k++) row[k] = (short)f2bf(W_edge[k * 1024 + co]);
            row[16] = (short)f2bf(b_edge[co]);
#pragma unroll
            for (int k = 17; k < WROW; k++) row[k] = 0;
            uint4* dstp = (uint4*)(WtP + co * WROW);       // co*48B, 16B-aligned
            dstp[0] = ((uint4*)row)[0]; dstp[1] = ((uint4*)row)[1]; dstp[2] = ((uint4*)row)[2];
            if (ab == 0 && tid < 8) WtP[1024 * WROW + tid] = 0;   // tail pad
        } else {
            int t = (ab - 4) * 256 + tid;
            float4 z = make_float4(0.f, 0.f, 0.f, 0.f);
            for (int i = t; i < NN * CH / 4; i += (AUX_BLOCKS - 4) * 256)
                ((float4*)aggr)[i] = z;
        }
        return;
    }

    // ---- input projection ----
#pragma unroll
    for (int i = 0; i < 16; i++) {
        int id = tid + 256 * i;           // id = k*32 + c
        int k = id >> 5, c = id & 31;
        Wt1[c * 136 + k] = (short)f2bf(W_in[id]);
    }
    __syncthreads();

    int wave = tid >> 6, lane = tid & 63;
    int n16 = lane & 15, quad = lane >> 4;
    int node0 = blockIdx.x * 64 + wave * 16;

    f32x4 D[2];
#pragma unroll
    for (int ch = 0; ch < 2; ch++) {
        float bb = b_in[ch * 16 + n16];
        D[ch] = (f32x4){bb, bb, bb, bb};
    }
    int arow = node0 + n16; if (arow >= NN) arow = NN - 1;
#pragma unroll
    for (int kb = 0; kb < 4; kb++) {
        const float4* xp = (const float4*)(x + (size_t)arow * FIN + kb * 32 + quad * 8);
        float4 xa = xp[0], xb = xp[1];
        bf16x8 A = (bf16x8){(short)f2bf(xa.x), (short)f2bf(xa.y), (short)f2bf(xa.z), (short)f2bf(xa.w),
                            (short)f2bf(xb.x), (short)f2bf(xb.y), (short)f2bf(xb.z), (short)f2bf(xb.w)};
#pragma unroll
        for (int ch = 0; ch < 2; ch++) {
            bf16x8 B = *(const bf16x8*)&Wt1[(ch * 16 + n16) * 136 + kb * 32 + quad * 8];
            D[ch] = __builtin_amdgcn_mfma_f32_16x16x32_bf16(A, B, D[ch], 0, 0, 0);
        }
    }
#pragma unroll
    for (int ch = 0; ch < 2; ch++)
#pragma unroll
        for (int r = 0; r < 4; r++) {
            int nn = node0 + quad * 4 + r;
            if (nn < NN) h_bf[(size_t)nn * CH + ch * 16 + n16] = f2bf(lrelu(D[ch][r]));
        }
}

// ---------------- Kernel 2: fused edge-NN + matvec + scatter
// Block = 256 thr = 4 waves; 256 edges/block; wave = 4 tiles x 16 edges.
// LDS: WtL 49.2KB + hsB(bf16) 16.9KB = 66.1KB -> 2 blocks/CU.
__global__ void __launch_bounds__(256, 2)
k_edge(const short* __restrict__ WtP,    // [1024][24] bf16 image (+pad)
       const float* __restrict__ ea,     // [EE][16] f32
       const int* __restrict__ src,
       const int* __restrict__ dst,
       const unsigned short* __restrict__ h_bf,  // [NN][32] bf16
       float* __restrict__ aggr) {
    __shared__ short WtL[WTP_SHORTS];          // 49168 B
    __shared__ unsigned short hsB[CH * 264];   // 16896 B, hsB[c][e], bf16

    int tid = threadIdx.x;
    int e0 = blockIdx.x * 256;

    // stage WtL: 13 uint4 per thread (52 wave-instructions/block)
#pragma unroll
    for (int j = 0; j < 13; j++) {
        int idx = tid + 256 * j;
        if (idx < WTP_SHORTS / 8) ((uint4*)WtL)[idx] = ((const uint4*)WtP)[idx];
    }
    // stage hsB (transposed, bf16): thread = block-edge
    {
        int e = e0 + tid; if (e >= EE) e = EE - 1;
        int s = src[e];
        const uint4* hp = (const uint4*)(h_bf + (size_t)s * CH);
        uint4 r0 = hp[0], r1 = hp[1], r2 = hp[2], r3 = hp[3];
        unsigned w[8] = {r0.x, r0.y, r0.z, r0.w, r1.x, r1.y, r1.z, r1.w};
        unsigned w2[8] = {r2.x, r2.y, r2.z, r2.w, r3.x, r3.y, r3.z, r3.w};
#pragma unroll
        for (int c2 = 0; c2 < 8; c2++) {
            hsB[(2 * c2) * 264 + tid]     = (unsigned short)(w[c2] & 0xffffu);
            hsB[(2 * c2 + 1) * 264 + tid] = (unsigned short)(w[c2] >> 16);
            hsB[(16 + 2 * c2) * 264 + tid]     = (unsigned short)(w2[c2] & 0xffffu);
            hsB[(16 + 2 * c2 + 1) * 264 + tid] = (unsigned short)(w2[c2] >> 16);
        }
    }
    __syncthreads();

    int wave = tid >> 6, lane = tid & 63;
    int n16 = lane & 15, quad = lane >> 4;
    int ebase = e0 + wave * 64;          // this wave's first edge
    int lbase = wave * 64;               // block-local

    // A fragments: quads 0,1 = f2bf(ea); quad 2 = {1.0,...} (bias row k=16); quad 3 = 0
    bf16x8 A[4];
#pragma unroll
    for (int t = 0; t < 4; t++) {
        bf16x8 a = (bf16x8){0,0,0,0,0,0,0,0};
        if (quad < 2) {
            int e = ebase + t * 16 + n16; if (e >= EE) e = EE - 1;
            const float4* p = (const float4*)(ea + (size_t)e * FE + quad * 8);
            float4 u = p[0], v = p[1];
            a = (bf16x8){(short)f2bf(u.x), (short)f2bf(u.y), (short)f2bf(u.z), (short)f2bf(u.w),
                         (short)f2bf(v.x), (short)f2bf(v.y), (short)f2bf(v.z), (short)f2bf(v.w)};
        } else if (quad == 2) {
            a[0] = (short)0x3F80;        // bf16 1.0 -> multiplies bias at k=16
        }
        A[t] = a;
    }

    f32x4 m[4][2];
#pragma unroll
    for (int t = 0; t < 4; t++) { m[t][0] = (f32x4){0,0,0,0}; m[t][1] = m[t][0]; }
    const f32x4 Z = (f32x4){0,0,0,0};

    const short* Bb = WtL + n16 * WROW + quad * 8;           // + cb*(16*WROW) imm
    const unsigned short* hb = hsB + lbase + quad * 4;       // + c*264 + t*16 imm

#pragma unroll 4
    for (int c = 0; c < 32; c++) {
        f32x4 hf[4];
#pragma unroll
        for (int t = 0; t < 4; t++) {
            uint2 raw = *(const uint2*)(hb + c * 264 + t * 16);   // ds_read_b64
            hf[t][0] = __uint_as_float(raw.x << 16);
            hf[t][1] = __uint_as_float(raw.x & 0xffff0000u);
            hf[t][2] = __uint_as_float(raw.y << 16);
            hf[t][3] = __uint_as_float(raw.y & 0xffff0000u);
        }
#pragma unroll
        for (int oh = 0; oh < 2; oh++) {
            bf16x8 B = *(const bf16x8*)(Bb + (c * 2 + oh) * (16 * WROW));
#pragma unroll
            for (int t = 0; t < 4; t++) {
                f32x4 D = __builtin_amdgcn_mfma_f32_16x16x32_bf16(A[t], B, Z, 0, 0, 0);
                m[t][oh] += hf[t] * lrelu4(D);    // v_pk_fma_f32
            }
        }
    }

    // scatter: lane holds msg for edge (tile t, row quad*4+r), col o = oh*16 + n16
#pragma unroll
    for (int t = 0; t < 4; t++)
#pragma unroll
        for (int r = 0; r < 4; r++) {
            int e = ebase + t * 16 + quad * 4 + r;
            if (e < EE) {
                int d = dst[e];
                unsafeAtomicAdd(&aggr[(size_t)d * CH + n16],      m[t][0][r]);
                unsafeAtomicAdd(&aggr[(size_t)d * CH + 16 + n16], m[t][1][r]);
            }
        }
}

// ---------------- Kernel 3 (MFMA): out = leaky(aggr + h@W_root + b_conv) @ W_out + b_out
__global__ void __launch_bounds__(256)
k_node(const float* __restrict__ aggr,
       const unsigned short* __restrict__ h_bf,
       const float* __restrict__ W_root,
       const float* __restrict__ b_conv,
       const float* __restrict__ W_out,
       const float* __restrict__ b_out,
       float* __restrict__ out) {
    __shared__ short WrB[CH * 40];   // W_root^T bf16: [o][c], stride 40 shorts
    __shared__ float WoS[CH];
    int tid = threadIdx.x;
    if (tid < 128) {
        int o = tid >> 2, c0 = (tid & 3) * 8;
        short tmp[8] __attribute__((aligned(16)));
#pragma unroll
        for (int j = 0; j < 8; j++) tmp[j] = (short)f2bf(W_root[(c0 + j) * CH + o]);
        *(bf16x8*)&WrB[o * 40 + c0] = *(bf16x8*)tmp;
    } else if (tid < 160) {
        WoS[tid - 128] = W_out[tid - 128];
    }
    __syncthreads();

    int wave = tid >> 6, lane = tid & 63;
    int n16 = lane & 15, quad = lane >> 4;
    int node0 = blockIdx.x * 64 + wave * 16;

    int arow = node0 + n16; if (arow >= NN) arow = NN - 1;
    bf16x8 A = *(const bf16x8*)(h_bf + (size_t)arow * CH + quad * 8);
    float bc0 = b_conv[n16], bc1 = b_conv[16 + n16];
    f32x4 C0, C1;
#pragma unroll
    for (int r = 0; r < 4; r++) {
        int nr = node0 + quad * 4 + r; int cr = (nr < NN) ? nr : NN - 1;
        C0[r] = aggr[(size_t)cr * CH + n16] + bc0;
        C1[r] = aggr[(size_t)cr * CH + 16 + n16] + bc1;
    }
    bf16x8 B0 = *(const bf16x8*)&WrB[n16 * 40 + quad * 8];
    bf16x8 B1 = *(const bf16x8*)&WrB[(16 + n16) * 40 + quad * 8];
    f32x4 D0 = __builtin_amdgcn_mfma_f32_16x16x32_bf16(A, B0, C0, 0, 0, 0);
    f32x4 D1 = __builtin_amdgcn_mfma_f32_16x16x32_bf16(A, B1, C1, 0, 0, 0);

    float w0 = WoS[n16], w1 = WoS[16 + n16];
    f32x4 p;
#pragma unroll
    for (int r = 0; r < 4; r++)
        p[r] = lrelu(D0[r]) * w0 + lrelu(D1[r]) * w1;
#pragma unroll
    for (int mk = 1; mk < 16; mk <<= 1) {
#pragma unroll
        for (int r = 0; r < 4; r++) p[r] += __shfl_xor(p[r], mk, 64);
    }
    if (n16 == 0) {
        float bo = b_out[0];
#pragma unroll
        for (int r = 0; r < 4; r++) {
            int nr = node0 + quad * 4 + r;
            if (nr < NN) out[nr] = p[r] + bo;
        }
    }
}

extern "C" void kernel_launch(void* const* d_in, const int* in_sizes, int n_in,
                              void* d_out, int out_size, void* d_ws, size_t ws_size,
                              hipStream_t stream) {
    const float* x      = (const float*)d_in[0];
    const int*   ei     = (const int*)d_in[1];
    const float* ea     = (const float*)d_in[2];
    const float* W_in   = (const float*)d_in[3];
    const float* b_in   = (const float*)d_in[4];
    const float* W_edge = (const float*)d_in[5];
    const float* b_edge = (const float*)d_in[6];
    const float* W_root = (const float*)d_in[7];
    const float* b_conv = (const float*)d_in[8];
    const float* W_out  = (const float*)d_in[9];
    const float* b_out  = (const float*)d_in[10];
    float* out = (float*)d_out;
    float* aggr = (float*)d_ws;                                 // [NN*CH] f32
    unsigned short* h_bf = (unsigned short*)(aggr + (size_t)NN * CH); // [NN*CH] bf16
    short* WtP  = (short*)(h_bf + (size_t)NN * CH);             // [WTP_SHORTS]

    k_pre<<<PROJ_BLOCKS + AUX_BLOCKS, 256, 0, stream>>>(x, W_in, b_in, W_edge, b_edge,
                                                        h_bf, aggr, WtP);
    k_edge<<<(EE + 255) / 256, 256, 0, stream>>>(WtP, ea, ei, ei + EE, h_bf, aggr);
    k_node<<<PROJ_BLOCKS, 256, 0, stream>>>(aggr, h_bf, W_root, b_conv, W_out, b_out, out);
}

// Round 10
// 170.122 us; speedup vs baseline: 1.6970x; 1.0846x over previous
//
#include <hip/hip_runtime.h>

#define NN 25000
#define EE 400000
#define FIN 128
#define FE 16
#define CH 32
#define SLOPE 0.01f
#define PROJ_BLOCKS 391   // ceil(25000/64)
#define AUX_BLOCKS 64     // 4 WtP-build + 60 aggr-zero
#define NTILES 3125       // EE/128
#define GRID_E 512        // persistent k_edge blocks, 2/CU
#define WROW 24                      // WtL row stride in shorts (48B); bias at k=16
#define WTP_SHORTS (1024 * WROW + 8) // +16B zero tail

typedef __attribute__((ext_vector_type(8))) short bf16x8;
typedef __attribute__((ext_vector_type(4))) float f32x4;

__device__ __forceinline__ float lrelu(float v) { return fmaxf(v, SLOPE * v); }

__device__ __forceinline__ f32x4 lrelu4(f32x4 v) {
    f32x4 s = v * SLOPE;
#if __has_builtin(__builtin_elementwise_max)
    return __builtin_elementwise_max(v, s);   // v_pk_max_f32
#else
    f32x4 r;
    r[0] = fmaxf(v[0], s[0]); r[1] = fmaxf(v[1], s[1]);
    r[2] = fmaxf(v[2], s[2]); r[3] = fmaxf(v[3], s[3]);
    return r;
#endif
}

__device__ __forceinline__ unsigned short f2bf(float f) {
    union { float f; unsigned u; } v; v.f = f;
    unsigned r = (v.u + 0x7fffu + ((v.u >> 16) & 1u)) >> 16;
    return (unsigned short)r;
}

// ---------------- Kernel 1: fused prep (R5/R8-proven)
// [0,PROJ): h = leaky(x@W_in+b_in) f32 via MFMA; [PROJ,+4): WtP; [+4,+64): zero aggr
__global__ void __launch_bounds__(256)
k_pre(const float* __restrict__ x, const float* __restrict__ W_in,
      const float* __restrict__ b_in, const float* __restrict__ W_edge,
      const float* __restrict__ b_edge,
      float* __restrict__ h, float* __restrict__ aggr, short* __restrict__ WtP) {
    __shared__ short Wt1[CH * 136];
    int tid = threadIdx.x;

    if (blockIdx.x >= PROJ_BLOCKS) {
        int ab = blockIdx.x - PROJ_BLOCKS;
        if (ab < 4) {
            int co = ab * 256 + tid;
            short row[WROW] __attribute__((aligned(16)));
#pragma unroll
            for (int k = 0; k < 16; k++) row[k] = (short)f2bf(W_edge[k * 1024 + co]);
            row[16] = (short)f2bf(b_edge[co]);
#pragma unroll
            for (int k = 17; k < WROW; k++) row[k] = 0;
            uint4* dq = (uint4*)(WtP + co * WROW);
            dq[0] = ((uint4*)row)[0]; dq[1] = ((uint4*)row)[1]; dq[2] = ((uint4*)row)[2];
            if (ab == 0 && tid < 8) WtP[1024 * WROW + tid] = 0;
        } else {
            int t = (ab - 4) * 256 + tid;
            float4 z = make_float4(0.f, 0.f, 0.f, 0.f);
            for (int i = t; i < NN * CH / 4; i += (AUX_BLOCKS - 4) * 256)
                ((float4*)aggr)[i] = z;
        }
        return;
    }

#pragma unroll
    for (int i = 0; i < 16; i++) {
        int id = tid + 256 * i;           // id = k*32 + c
        Wt1[(id & 31) * 136 + (id >> 5)] = (short)f2bf(W_in[id]);
    }
    __syncthreads();

    int wave = tid >> 6, lane = tid & 63;
    int n16 = lane & 15, quad = lane >> 4;
    int node0 = blockIdx.x * 64 + wave * 16;

    f32x4 D[2];
#pragma unroll
    for (int ch = 0; ch < 2; ch++) {
        float bb = b_in[ch * 16 + n16];
        D[ch] = (f32x4){bb, bb, bb, bb};
    }
    int arow = node0 + n16; if (arow >= NN) arow = NN - 1;
#pragma unroll
    for (int kb = 0; kb < 4; kb++) {
        const float4* xp = (const float4*)(x + (size_t)arow * FIN + kb * 32 + quad * 8);
        float4 xa = xp[0], xb = xp[1];
        bf16x8 A = (bf16x8){(short)f2bf(xa.x), (short)f2bf(xa.y), (short)f2bf(xa.z), (short)f2bf(xa.w),
                            (short)f2bf(xb.x), (short)f2bf(xb.y), (short)f2bf(xb.z), (short)f2bf(xb.w)};
#pragma unroll
        for (int ch = 0; ch < 2; ch++) {
            bf16x8 B = *(const bf16x8*)&Wt1[(ch * 16 + n16) * 136 + kb * 32 + quad * 8];
            D[ch] = __builtin_amdgcn_mfma_f32_16x16x32_bf16(A, B, D[ch], 0, 0, 0);
        }
    }
#pragma unroll
    for (int ch = 0; ch < 2; ch++)
#pragma unroll
        for (int r = 0; r < 4; r++) {
            int nn = node0 + quad * 4 + r;
            if (nn < NN) h[(size_t)nn * CH + ch * 16 + n16] = lrelu(D[ch][r]);
        }
}

// ---------------- Kernel 2: persistent fused edge-NN + matvec + scatter
// R5 tile shape (128 edges/tile, 2 tiles/wave of 16), WtL staged ONCE per block,
// next tile's h-gather / ea / dst prefetched into registers during compute.
__global__ void __launch_bounds__(256, 2)
k_edge(const short* __restrict__ WtP,    // [1024][24] bf16 image (+pad)
       const float* __restrict__ ea,     // [EE][16] f32
       const int* __restrict__ src,
       const int* __restrict__ dst,
       const float* __restrict__ h,      // [NN][32] f32
       float* __restrict__ aggr) {
    __shared__ short WtL[WTP_SHORTS];    // 49168 B
    __shared__ float hsT[CH * 132];      // 16896 B, hsT[c][e]

    int tid = threadIdx.x;
    int wave = tid >> 6, lane = tid & 63;
    int n16 = lane & 15, quad = lane >> 4;
    int t0 = wave * 32, t1 = t0 + 16;
    int eh = tid >> 1, half = tid & 1;   // staging role: edge eh, row half

    // stage WtL once per block
#pragma unroll
    for (int j = 0; j < 13; j++) {
        int idx = tid + 256 * j;
        if (idx < WTP_SHORTS / 8) ((uint4*)WtL)[idx] = ((const uint4*)WtP)[idx];
    }

    const short* Bb = WtL + n16 * WROW + quad * 8;   // + cb*(16*WROW) imm
    const float* h0b = hsT + t0 + quad * 4;          // + c*132 imm
    const float* h1b = hsT + t1 + quad * 4;
    const f32x4 Z = (f32x4){0, 0, 0, 0};

    // ---- prefetch registers (next tile) ----
    float vv[16] __attribute__((aligned(16)));
    bf16x8 An0, An1;
    int dn0[4], dn1[4];

    // prefetch first tile
    {
        int e0 = blockIdx.x * 128;
        int s = src[e0 + eh];
        const float4* hp = (const float4*)(h + (size_t)s * CH + half * 16);
        *(float4*)&vv[0] = hp[0]; *(float4*)&vv[4] = hp[1];
        *(float4*)&vv[8] = hp[2]; *(float4*)&vv[12] = hp[3];
        An0 = (bf16x8){0,0,0,0,0,0,0,0}; An1 = An0;
        if (quad < 2) {
            const float4* p0 = (const float4*)(ea + (size_t)(e0 + t0 + n16) * FE + quad * 8);
            float4 a = p0[0], b = p0[1];
            An0 = (bf16x8){(short)f2bf(a.x), (short)f2bf(a.y), (short)f2bf(a.z), (short)f2bf(a.w),
                           (short)f2bf(b.x), (short)f2bf(b.y), (short)f2bf(b.z), (short)f2bf(b.w)};
            const float4* p1 = (const float4*)(ea + (size_t)(e0 + t1 + n16) * FE + quad * 8);
            a = p1[0]; b = p1[1];
            An1 = (bf16x8){(short)f2bf(a.x), (short)f2bf(a.y), (short)f2bf(a.z), (short)f2bf(a.w),
                           (short)f2bf(b.x), (short)f2bf(b.y), (short)f2bf(b.z), (short)f2bf(b.w)};
        } else if (quad == 2) {
            An0[0] = (short)0x3F80; An1[0] = (short)0x3F80;
        }
#pragma unroll
        for (int r = 0; r < 4; r++) {
            dn0[r] = dst[e0 + t0 + quad * 4 + r];
            dn1[r] = dst[e0 + t1 + quad * 4 + r];
        }
    }

    for (int tile = blockIdx.x; tile < NTILES; tile += GRID_E) {
        __syncthreads();   // prev tile's hsT readers done (iter0: covers WtL staging)
        // commit prefetched h rows to LDS
#pragma unroll
        for (int j = 0; j < 16; j++) hsT[(half * 16 + j) * 132 + eh] = vv[j];
        __syncthreads();

        // rotate prefetched -> current
        bf16x8 A0 = An0, A1 = An1;
        int dc0[4], dc1[4];
#pragma unroll
        for (int r = 0; r < 4; r++) { dc0[r] = dn0[r]; dc1[r] = dn1[r]; }

        // prefetch next tile (global loads overlap the MFMA loop below)
        int ntile = tile + GRID_E;
        if (ntile < NTILES) {
            int e0 = ntile * 128;
            int s = src[e0 + eh];
            const float4* hp = (const float4*)(h + (size_t)s * CH + half * 16);
            *(float4*)&vv[0] = hp[0]; *(float4*)&vv[4] = hp[1];
            *(float4*)&vv[8] = hp[2]; *(float4*)&vv[12] = hp[3];
            if (quad < 2) {
                const float4* p0 = (const float4*)(ea + (size_t)(e0 + t0 + n16) * FE + quad * 8);
                float4 a = p0[0], b = p0[1];
                An0 = (bf16x8){(short)f2bf(a.x), (short)f2bf(a.y), (short)f2bf(a.z), (short)f2bf(a.w),
                               (short)f2bf(b.x), (short)f2bf(b.y), (short)f2bf(b.z), (short)f2bf(b.w)};
                const float4* p1 = (const float4*)(ea + (size_t)(e0 + t1 + n16) * FE + quad * 8);
                a = p1[0]; b = p1[1];
                An1 = (bf16x8){(short)f2bf(a.x), (short)f2bf(a.y), (short)f2bf(a.z), (short)f2bf(a.w),
                               (short)f2bf(b.x), (short)f2bf(b.y), (short)f2bf(b.z), (short)f2bf(b.w)};
            }
#pragma unroll
            for (int r = 0; r < 4; r++) {
                dn0[r] = dst[e0 + t0 + quad * 4 + r];
                dn1[r] = dst[e0 + t1 + quad * 4 + r];
            }
        }

        // ---- main MFMA loop (R5-proven) ----
        f32x4 m0[2], m1[2];
        m0[0] = Z; m0[1] = Z; m1[0] = Z; m1[1] = Z;
#pragma unroll
        for (int c4 = 0; c4 < 8; c4++) {
#pragma unroll
            for (int cc = 0; cc < 4; cc++) {
                int c = c4 * 4 + cc;
                f32x4 hc0 = *(const f32x4*)(h0b + c * 132);
                f32x4 hc1 = *(const f32x4*)(h1b + c * 132);
#pragma unroll
                for (int oh = 0; oh < 2; oh++) {
                    int cb = c * 2 + oh;
                    bf16x8 B = *(const bf16x8*)(Bb + cb * (16 * WROW));
                    f32x4 D0 = __builtin_amdgcn_mfma_f32_16x16x32_bf16(A0, B, Z, 0, 0, 0);
                    f32x4 D1 = __builtin_amdgcn_mfma_f32_16x16x32_bf16(A1, B, Z, 0, 0, 0);
                    m0[oh] += hc0 * lrelu4(D0);
                    m1[oh] += hc1 * lrelu4(D1);
                }
            }
        }

        // scatter
#pragma unroll
        for (int r = 0; r < 4; r++) {
#pragma unroll
            for (int oh = 0; oh < 2; oh++) {
                unsafeAtomicAdd(&aggr[(size_t)dc0[r] * CH + oh * 16 + n16], m0[oh][r]);
                unsafeAtomicAdd(&aggr[(size_t)dc1[r] * CH + oh * 16 + n16], m1[oh][r]);
            }
        }
    }
}

// ---------------- Kernel 3 (MFMA): out = leaky(aggr + h@W_root + b_conv) @ W_out + b_out
__global__ void __launch_bounds__(256)
k_node(const float* __restrict__ aggr,
       const float* __restrict__ h,
       const float* __restrict__ W_root,
       const float* __restrict__ b_conv,
       const float* __restrict__ W_out,
       const float* __restrict__ b_out,
       float* __restrict__ out) {
    __shared__ short WrB[CH * 40];
    __shared__ float WoS[CH];
    int tid = threadIdx.x;
    if (tid < 128) {
        int o = tid >> 2, c0 = (tid & 3) * 8;
        short tmp[8] __attribute__((aligned(16)));
#pragma unroll
        for (int j = 0; j < 8; j++) tmp[j] = (short)f2bf(W_root[(c0 + j) * CH + o]);
        *(bf16x8*)&WrB[o * 40 + c0] = *(bf16x8*)tmp;
    } else if (tid < 160) {
        WoS[tid - 128] = W_out[tid - 128];
    }
    __syncthreads();

    int wave = tid >> 6, lane = tid & 63;
    int n16 = lane & 15, quad = lane >> 4;
    int node0 = blockIdx.x * 64 + wave * 16;

    int arow = node0 + n16; if (arow >= NN) arow = NN - 1;
    const float4* hp = (const float4*)(h + (size_t)arow * CH + quad * 8);
    float4 ha = hp[0], hb = hp[1];
    bf16x8 A = (bf16x8){(short)f2bf(ha.x), (short)f2bf(ha.y), (short)f2bf(ha.z), (short)f2bf(ha.w),
                        (short)f2bf(hb.x), (short)f2bf(hb.y), (short)f2bf(hb.z), (short)f2bf(hb.w)};
    float bc0 = b_conv[n16], bc1 = b_conv[16 + n16];
    f32x4 C0, C1;
#pragma unroll
    for (int r = 0; r < 4; r++) {
        int nr = node0 + quad * 4 + r; int cr = (nr < NN) ? nr : NN - 1;
        C0[r] = aggr[(size_t)cr * CH + n16] + bc0;
        C1[r] = aggr[(size_t)cr * CH + 16 + n16] + bc1;
    }
    bf16x8 B0 = *(const bf16x8*)&WrB[n16 * 40 + quad * 8];
    bf16x8 B1 = *(const bf16x8*)&WrB[(16 + n16) * 40 + quad * 8];
    f32x4 D0 = __builtin_amdgcn_mfma_f32_16x16x32_bf16(A, B0, C0, 0, 0, 0);
    f32x4 D1 = __builtin_amdgcn_mfma_f32_16x16x32_bf16(A, B1, C1, 0, 0, 0);

    float w0 = WoS[n16], w1 = WoS[16 + n16];
    f32x4 p;
#pragma unroll
    for (int r = 0; r < 4; r++)
        p[r] = lrelu(D0[r]) * w0 + lrelu(D1[r]) * w1;
#pragma unroll
    for (int mk = 1; mk < 16; mk <<= 1) {
#pragma unroll
        for (int r = 0; r < 4; r++) p[r] += __shfl_xor(p[r], mk, 64);
    }
    if (n16 == 0) {
        float bo = b_out[0];
#pragma unroll
        for (int r = 0; r < 4; r++) {
            int nr = node0 + quad * 4 + r;
            if (nr < NN) out[nr] = p[r] + bo;
        }
    }
}

extern "C" void kernel_launch(void* const* d_in, const int* in_sizes, int n_in,
                              void* d_out, int out_size, void* d_ws, size_t ws_size,
                              hipStream_t stream) {
    const float* x      = (const float*)d_in[0];
    const int*   ei     = (const int*)d_in[1];
    const float* ea     = (const float*)d_in[2];
    const float* W_in   = (const float*)d_in[3];
    const float* b_in   = (const float*)d_in[4];
    const float* W_edge = (const float*)d_in[5];
    const float* b_edge = (const float*)d_in[6];
    const float* W_root = (const float*)d_in[7];
    const float* b_conv = (const float*)d_in[8];
    const float* W_out  = (const float*)d_in[9];
    const float* b_out  = (const float*)d_in[10];
    float* out  = (float*)d_out;
    float* h    = (float*)d_ws;                       // [NN*CH] f32
    float* aggr = h + (size_t)NN * CH;                // [NN*CH] f32
    short* WtP  = (short*)(aggr + (size_t)NN * CH);   // [WTP_SHORTS] bf16 image

    k_pre<<<PROJ_BLOCKS + AUX_BLOCKS, 256, 0, stream>>>(x, W_in, b_in, W_edge, b_edge,
                                                        h, aggr, WtP);
    k_edge<<<GRID_E, 256, 0, stream>>>(WtP, ea, ei, ei + EE, h, aggr);
    k_node<<<PROJ_BLOCKS, 256, 0, stream>>>(aggr, h, W_root, b_conv, W_out, b_out, out);
}